// Round 5
// baseline (28.511 us; speedup 1.0000x reference)
//
#include <hip/hip_runtime.h>
#include <math.h>

// Morph2d: weighted 3x3 window min/max lerp.
// s = x_pad + 10*bias[c] (pad cell -> biasv, since raw pad = 0); tap = s * k[c,i,j]
// out = vmin + (vmax - vmin) * sigmoid(10*percentile[c]) - 10*bias[c]
//
// R5: TW=8 x TH=2 tile/thread, bias folded at load (no bk[] -> ~64-72 VGPR,
// 8 waves/SIMD cap), 802,816 threads = 49 waves/CU demand -> occupancy-saturated.

#define B_ 16
#define C_ 64
#define H_ 112
#define W_ 112
#define TW 8
#define TH 2
#define GX (W_ / TW)   // 14
#define GY (H_ / TH)   // 56

typedef float f32x4 __attribute__((ext_vector_type(4)));

__global__ __launch_bounds__(256) void morph2d_kernel(
    const float* __restrict__ x,
    const float* __restrict__ kern,   // (1,C,3,3)
    const float* __restrict__ bias,   // (C,)
    const float* __restrict__ perc,   // (C,)
    float* __restrict__ out)
{
    const int total = B_ * C_ * GY * GX;  // 802,816
    int t = blockIdx.x * blockDim.x + threadIdx.x;
    if (t >= total) return;

    int gx = t % GX;
    int r1 = t / GX;
    int ys = r1 % GY;
    int bc = r1 / GY;       // b*C + c
    int c  = bc % C_;

    float biasv = bias[c] * 10.0f;
    float p = 1.0f / (1.0f + expf(-perc[c] * 10.0f));

    const float* plane  = x   + (size_t)bc * (H_ * W_);
    float*       oplane = out + (size_t)bc * (H_ * W_);
    const int x0 = gx * TW;
    const int y0 = ys * TH;

    // Preload TH+2 = 4 rows, cols x0-1 .. x0+8, with biasv pre-added
    // (pad cell == biasv). All loads independent -> max MLP, one vmcnt wait.
    float s[TH + 2][TW + 2];
    #pragma unroll
    for (int i = 0; i < TH + 2; ++i) {
        int yy = y0 + i - 1;
        if ((unsigned)yy < (unsigned)H_) {
            const float* rp = plane + yy * W_ + x0;
            f32x4 a  = *reinterpret_cast<const f32x4*>(rp);
            f32x4 b4 = *reinterpret_cast<const f32x4*>(rp + 4);
            s[i][1] = a.x  + biasv;  s[i][2] = a.y  + biasv;
            s[i][3] = a.z  + biasv;  s[i][4] = a.w  + biasv;
            s[i][5] = b4.x + biasv;  s[i][6] = b4.y + biasv;
            s[i][7] = b4.z + biasv;  s[i][8] = b4.w + biasv;
            s[i][0] = (x0 > 0)       ? rp[-1] + biasv : biasv;
            s[i][9] = (x0 + TW < W_) ? rp[TW] + biasv : biasv;
        } else {
            #pragma unroll
            for (int j = 0; j < TW + 2; ++j) s[i][j] = biasv;
        }
    }

    float k[9];
    #pragma unroll
    for (int i = 0; i < 9; ++i) k[i] = kern[c * 9 + i];

    #pragma unroll
    for (int r = 0; r < TH; ++r) {
        float o[TW];
        #pragma unroll
        for (int q = 0; q < TW; ++q) {
            float t0 = s[r][q]     * k[0];
            float t1 = s[r][q + 1] * k[1];
            float t2 = s[r][q + 2] * k[2];
            float vmax = fmaxf(fmaxf(t0, t1), t2);
            float vmin = fminf(fminf(t0, t1), t2);
            t0 = s[r + 1][q]     * k[3];
            t1 = s[r + 1][q + 1] * k[4];
            t2 = s[r + 1][q + 2] * k[5];
            vmax = fmaxf(vmax, fmaxf(fmaxf(t0, t1), t2));
            vmin = fminf(vmin, fminf(fminf(t0, t1), t2));
            t0 = s[r + 2][q]     * k[6];
            t1 = s[r + 2][q + 1] * k[7];
            t2 = s[r + 2][q + 2] * k[8];
            vmax = fmaxf(vmax, fmaxf(fmaxf(t0, t1), t2));
            vmin = fminf(vmin, fminf(fminf(t0, t1), t2));
            o[q] = fmaf(vmax - vmin, p, vmin) - biasv;
        }

        float* orow = oplane + (y0 + r) * W_ + x0;
        f32x4 lo = { o[0], o[1], o[2], o[3] };
        f32x4 hi = { o[4], o[5], o[6], o[7] };
        __builtin_nontemporal_store(lo, reinterpret_cast<f32x4*>(orow));
        __builtin_nontemporal_store(hi, reinterpret_cast<f32x4*>(orow + 4));
    }
}

extern "C" void kernel_launch(void* const* d_in, const int* in_sizes, int n_in,
                              void* d_out, int out_size, void* d_ws, size_t ws_size,
                              hipStream_t stream) {
    const float* x    = (const float*)d_in[0];
    const float* kern = (const float*)d_in[1];
    const float* bias = (const float*)d_in[2];
    const float* perc = (const float*)d_in[3];
    float* out = (float*)d_out;

    const int total = B_ * C_ * GY * GX;              // 802,816
    const int block = 256;
    const int grid  = (total + block - 1) / block;    // 3136
    morph2d_kernel<<<grid, block, 0, stream>>>(x, kern, bias, perc, out);
}